// Round 4
// baseline (2033.242 us; speedup 1.0000x reference)
//
#include <hip/hip_runtime.h>

#define N_NODES 100000
#define N_EDGES 1000000
#define N_GRAPHS 1000
#define EMBED 64
#define OUT_DIM 128
#define BN_EPS 1e-5f
#define NBLK ((N_NODES + 255) / 256)   // 391 scan blocks

// ---------------- one-time structure kernels ----------------

__global__ void embed_kernel(const int* __restrict__ nfeat,
                             const float* __restrict__ atom_embed,
                             float4* __restrict__ h4) {
    int idx = blockIdx.x * blockDim.x + threadIdx.x;   // one float4 each
    if (idx >= N_NODES * 16) return;
    int v = idx >> 4, q = idx & 15;
    const float4* ae = (const float4*)atom_embed;
    h4[idx] = ae[nfeat[v] * 16 + q];
}

__global__ void deg_kernel(const int* __restrict__ dst, int* __restrict__ deg) {
    int e = blockIdx.x * blockDim.x + threadIdx.x;
    if (e < N_EDGES) atomicAdd(&deg[dst[e]], 1);
}

__global__ void scan1_kernel(const int* __restrict__ deg, int* __restrict__ bsum) {
    __shared__ int sm[256];
    int v = blockIdx.x * 256 + threadIdx.x;
    sm[threadIdx.x] = (v < N_NODES) ? deg[v] : 0;
    __syncthreads();
    for (int off = 128; off > 0; off >>= 1) {
        if (threadIdx.x < off) sm[threadIdx.x] += sm[threadIdx.x + off];
        __syncthreads();
    }
    if (threadIdx.x == 0) bsum[blockIdx.x] = sm[0];
}

__global__ void scan2_kernel(const int* __restrict__ bsum, int* __restrict__ bpre) {
    __shared__ int sm[512];
    int i = threadIdx.x;
    int orig = (i < NBLK) ? bsum[i] : 0;
    sm[i] = orig;
    __syncthreads();
    for (int off = 1; off < 512; off <<= 1) {
        int val = sm[i];
        if (i >= off) val += sm[i - off];
        __syncthreads();
        sm[i] = val;
        __syncthreads();
    }
    if (i < NBLK) bpre[i] = sm[i] - orig;   // exclusive prefix of block sums
}

__global__ void scan3_kernel(const int* __restrict__ deg, const int* __restrict__ bpre,
                             int* __restrict__ rowptr, int* __restrict__ cursor) {
    __shared__ int sm[256];
    int v = blockIdx.x * 256 + threadIdx.x;
    int d = (v < N_NODES) ? deg[v] : 0;
    sm[threadIdx.x] = d;
    __syncthreads();
    for (int off = 1; off < 256; off <<= 1) {
        int val = sm[threadIdx.x];
        if (threadIdx.x >= off) val += sm[threadIdx.x - off];
        __syncthreads();
        sm[threadIdx.x] = val;
        __syncthreads();
    }
    if (v < N_NODES) {
        int ex = bpre[blockIdx.x] + sm[threadIdx.x] - d;  // exclusive scan
        rowptr[v] = ex;
        cursor[v] = ex;
    }
    if (v == 0) rowptr[N_NODES] = N_EDGES;
}

// bucket edges by dst; payload packs src (20 bits) + efeat (bits 20+)
__global__ void scatter_kernel(const int* __restrict__ src, const int* __restrict__ dst,
                               const int* __restrict__ efeat,
                               int* __restrict__ cursor, unsigned* __restrict__ ebuf) {
    int e = blockIdx.x * blockDim.x + threadIdx.x;
    if (e >= N_EDGES) return;
    int t = dst[e];
    int pos = atomicAdd(&cursor[t], 1);
    ebuf[pos] = (unsigned)src[e] | ((unsigned)efeat[e] << 20);
}

// graph_ids is sorted: find segment boundaries. gstart has N_GRAPHS+1 entries.
__global__ void gbound_kernel(const int* __restrict__ gid, int* __restrict__ gstart) {
    int v = blockIdx.x * blockDim.x + threadIdx.x;
    if (v > N_NODES) return;
    int cur  = (v < N_NODES) ? gid[v] : N_GRAPHS;
    int prev = (v == 0) ? -1 : gid[v - 1];
    for (int g = prev + 1; g <= cur; ++g) gstart[g] = v;
}

// ---------------- per-layer fused conv ----------------
// Wave = 4 x 16-lane slots; slot owns one NODE, lane = float4 slice of 64 dims.
// Gather: 2x manual unroll -> up to 8 independent 256B gathers in flight/wave.
// GEMM: t staged via wave-private LDS slab; wave-uniform ds_read_b128 broadcast;
// each Ws value reused across the wave's 4 nodes.
__launch_bounds__(256, 6)
__global__ void fused_conv_kernel(const int* __restrict__ rowptr,
                                  const unsigned* __restrict__ ebuf,
                                  const float* __restrict__ bond,   // [5,64]
                                  const float4* __restrict__ h4,
                                  const float* __restrict__ W,      // [64,64]
                                  const float* __restrict__ bias,   // [64]
                                  float* __restrict__ h_pre,
                                  float* __restrict__ colsum,
                                  float* __restrict__ colsq) {
    __shared__ float  Ws[EMBED * EMBED];     // 16 KB
    __shared__ float4 bond4[5 * 16];         // 320 B
    __shared__ float  tmat[4][4][EMBED];     // 4 KB: [wave][slot][dim], reused for BN red

    int lane = threadIdx.x & 63;
    int wblk = threadIdx.x >> 6;
    int slot = lane >> 4;       // which node of the group of 4
    int sub  = lane & 15;       // float4 index (dims 4*sub..4*sub+3)

    for (int i = threadIdx.x; i < EMBED * EMBED; i += 256) Ws[i] = W[i];
    if (threadIdx.x < 5 * 16) bond4[threadIdx.x] = ((const float4*)bond)[threadIdx.x];
    __syncthreads();

    float bj = bias[lane];
    float lsum = 0.0f, lsq = 0.0f;

    int gwid = blockIdx.x * 4 + wblk;       // global wave id
    int nw   = gridDim.x * 4;

    for (int v0 = gwid * 4; v0 < N_NODES; v0 += nw * 4) {
        int v  = v0 + slot;
        int vc = (v < N_NODES) ? v : 0;
        int rb = rowptr[vc];
        int re = (v < N_NODES) ? rowptr[vc + 1] : rb;

        float4 a = {0.f, 0.f, 0.f, 0.f};
        for (int e = rb; e < re; e += 2) {
            unsigned p0 = ebuf[e];
            int  ok1 = (e + 1 < re);
            unsigned p1 = ebuf[ok1 ? e + 1 : e];
            float m1 = ok1 ? 1.0f : 0.0f;
            int s0 = (int)(p0 & 0xFFFFFu), b0 = (int)(p0 >> 20);
            int s1 = (int)(p1 & 0xFFFFFu), b1 = (int)(p1 >> 20);
            float4 h0 = h4[s0 * 16 + sub];
            float4 h1 = h4[s1 * 16 + sub];
            float4 c0 = bond4[b0 * 16 + sub];
            float4 c1 = bond4[b1 * 16 + sub];
            a.x += fmaxf(h0.x + c0.x, 0.f) + m1 * fmaxf(h1.x + c1.x, 0.f);
            a.y += fmaxf(h0.y + c0.y, 0.f) + m1 * fmaxf(h1.y + c1.y, 0.f);
            a.z += fmaxf(h0.z + c0.z, 0.f) + m1 * fmaxf(h1.z + c1.z, 0.f);
            a.w += fmaxf(h0.w + c0.w, 0.f) + m1 * fmaxf(h1.w + c1.w, 0.f);
        }
        float inv = 1.0f / fmaxf((float)(re - rb), 1.0f);
        float4 hr = h4[vc * 16 + sub];
        float4 t;
        t.x = a.x * inv + hr.x;
        t.y = a.y * inv + hr.y;
        t.z = a.z * inv + hr.z;
        t.w = a.w * inv + hr.w;
        *(float4*)&tmat[wblk][slot][sub * 4] = t;   // wave-private; lgkmcnt guards reads

        float o0 = bj, o1 = bj, o2 = bj, o3 = bj;
#pragma unroll
        for (int dq = 0; dq < 16; ++dq) {
            float w0 = Ws[(dq * 4 + 0) * EMBED + lane];
            float w1 = Ws[(dq * 4 + 1) * EMBED + lane];
            float w2 = Ws[(dq * 4 + 2) * EMBED + lane];
            float w3 = Ws[(dq * 4 + 3) * EMBED + lane];
            float4 t0 = *(const float4*)&tmat[wblk][0][dq * 4];
            float4 t1 = *(const float4*)&tmat[wblk][1][dq * 4];
            float4 t2 = *(const float4*)&tmat[wblk][2][dq * 4];
            float4 t3 = *(const float4*)&tmat[wblk][3][dq * 4];
            o0 += t0.x * w0 + t0.y * w1 + t0.z * w2 + t0.w * w3;
            o1 += t1.x * w0 + t1.y * w1 + t1.z * w2 + t1.w * w3;
            o2 += t2.x * w0 + t2.y * w1 + t2.z * w2 + t2.w * w3;
            o3 += t3.x * w0 + t3.y * w1 + t3.z * w2 + t3.w * w3;
        }
        float oo[4] = {o0, o1, o2, o3};
#pragma unroll
        for (int k = 0; k < 4; ++k) {
            int vv = v0 + k;
            if (vv < N_NODES) {
                h_pre[vv * EMBED + lane] = oo[k];
                lsum += oo[k];
                lsq  += oo[k] * oo[k];
            }
        }
    }

    // BN partial reduction; reuse tmat (each wave writes only its own slice)
    tmat[wblk][0][lane] = lsum;
    tmat[wblk][1][lane] = lsq;
    __syncthreads();
    if (wblk == 0) {
        float s = tmat[0][0][lane] + tmat[1][0][lane] + tmat[2][0][lane] + tmat[3][0][lane];
        float q = tmat[0][1][lane] + tmat[1][1][lane] + tmat[2][1][lane] + tmat[3][1][lane];
        atomicAdd(&colsum[lane], s);
        atomicAdd(&colsq[lane], q);
    }
}

// batchnorm + optional relu + residual (in-place update of h), float4
__global__ void bn_kernel(const float4* __restrict__ h_pre4,
                          const float* __restrict__ colsum,
                          const float* __restrict__ colsq,
                          const float* __restrict__ gamma,
                          const float* __restrict__ beta,
                          float4* __restrict__ h4,
                          int do_relu) {
    int idx = blockIdx.x * blockDim.x + threadIdx.x;   // one float4
    if (idx >= N_NODES * 16) return;
    int q = idx & 15;            // dims 4q..4q+3
    const float invN = 1.0f / (float)N_NODES;
    float4 p = h_pre4[idx];
    float4 r = h4[idx];
    float o[4] = {p.x, p.y, p.z, p.w};
    float rr[4] = {r.x, r.y, r.z, r.w};
#pragma unroll
    for (int c = 0; c < 4; ++c) {
        int j = q * 4 + c;
        float mu  = colsum[j] * invN;
        float var = colsq[j] * invN - mu * mu;
        float inv = rsqrtf(var + BN_EPS);
        float y = (o[c] - mu) * inv * gamma[j] + beta[j];
        if (do_relu) y = fmaxf(y, 0.0f);
        o[c] = y + rr[c];
    }
    float4 res = {o[0], o[1], o[2], o[3]};
    h4[idx] = res;
}

// one wave per graph: sequential coalesced mean over its node range (gid sorted)
__global__ void pool_kernel(const int* __restrict__ gstart,
                            const float* __restrict__ h,
                            float* __restrict__ gmean) {
    int g    = (blockIdx.x * blockDim.x + threadIdx.x) >> 6;
    int lane = threadIdx.x & 63;
    if (g >= N_GRAPHS) return;
    int b = gstart[g], e = gstart[g + 1];
    float s = 0.0f;
    for (int v = b; v < e; ++v) s += h[v * EMBED + lane];
    gmean[g * EMBED + lane] = s / fmaxf((float)(e - b), 1.0f);
}

// [1000,64] @ [64,128] + b, one block (128 threads) per graph
__global__ void pred_kernel(const float* __restrict__ gmean,
                            const float* __restrict__ W,   // [64,128]
                            const float* __restrict__ b,   // [128]
                            float* __restrict__ out) {
    __shared__ float gm[EMBED];
    int g = blockIdx.x;
    int j = threadIdx.x;  // 0..127
    if (j < EMBED) gm[j] = gmean[g * EMBED + j];
    __syncthreads();
    float acc = b[j];
#pragma unroll
    for (int d = 0; d < EMBED; ++d)
        acc += gm[d] * W[d * OUT_DIM + j];
    out[g * OUT_DIM + j] = acc;
}

// ---------------- launch ----------------

extern "C" void kernel_launch(void* const* d_in, const int* in_sizes, int n_in,
                              void* d_out, int out_size, void* d_ws, size_t ws_size,
                              hipStream_t stream) {
    const int*   nfeat      = (const int*)d_in[0];
    const int*   efeat      = (const int*)d_in[1];
    const int*   src        = (const int*)d_in[2];
    const int*   dst        = (const int*)d_in[3];
    const int*   gid        = (const int*)d_in[4];
    const float* atom_embed = (const float*)d_in[5];
    const float* bond_embed = (const float*)d_in[6];  // [3,5,64]
    const float* conv_W     = (const float*)d_in[7];  // [3,64,64]
    const float* conv_b     = (const float*)d_in[8];  // [3,64]
    const float* bn_gamma   = (const float*)d_in[9];  // [3,64]
    const float* bn_beta    = (const float*)d_in[10]; // [3,64]
    const float* pred_W     = (const float*)d_in[11]; // [64,128]
    const float* pred_b     = (const float*)d_in[12]; // [128]
    float* out = (float*)d_out;

    char* wsb = (char*)d_ws;
    float*    h      = (float*)wsb;                     wsb += (size_t)N_NODES * EMBED * 4;
    float*    h_pre  = (float*)wsb;                     wsb += (size_t)N_NODES * EMBED * 4;
    int*      deg    = (int*)wsb;                       wsb += (size_t)N_NODES * 4;
    int*      rowptr = (int*)wsb;                       wsb += (size_t)(N_NODES + 1) * 4;
    int*      cursor = (int*)wsb;                       wsb += (size_t)N_NODES * 4;
    int*      bsum   = (int*)wsb;                       wsb += (size_t)NBLK * 4;
    int*      bpre   = (int*)wsb;                       wsb += (size_t)NBLK * 4;
    unsigned* ebuf   = (unsigned*)wsb;                  wsb += (size_t)N_EDGES * 4;
    int*      gstart = (int*)wsb;                       wsb += (size_t)(N_GRAPHS + 1) * 4;
    float*    gmean  = (float*)wsb;                     wsb += (size_t)N_GRAPHS * EMBED * 4;
    float*    colsum = (float*)wsb;                     wsb += (size_t)EMBED * 4;
    float*    colsq  = (float*)wsb;                     wsb += (size_t)EMBED * 4;

    hipMemsetAsync(deg, 0, N_NODES * sizeof(int), stream);

    embed_kernel<<<(N_NODES * 16 + 255) / 256, 256, 0, stream>>>(nfeat, atom_embed, (float4*)h);
    deg_kernel<<<(N_EDGES + 255) / 256, 256, 0, stream>>>(dst, deg);
    scan1_kernel<<<NBLK, 256, 0, stream>>>(deg, bsum);
    scan2_kernel<<<1, 512, 0, stream>>>(bsum, bpre);
    scan3_kernel<<<NBLK, 256, 0, stream>>>(deg, bpre, rowptr, cursor);
    scatter_kernel<<<(N_EDGES + 255) / 256, 256, 0, stream>>>(src, dst, efeat, cursor, ebuf);
    gbound_kernel<<<(N_NODES + 256) / 256, 256, 0, stream>>>(gid, gstart);

    for (int i = 0; i < 3; ++i) {
        hipMemsetAsync(colsum, 0, 2 * EMBED * sizeof(float), stream);  // colsum+colsq
        fused_conv_kernel<<<1536, 256, 0, stream>>>(
            rowptr, ebuf, bond_embed + i * 5 * EMBED, (const float4*)h,
            conv_W + i * EMBED * EMBED, conv_b + i * EMBED,
            h_pre, colsum, colsq);
        bn_kernel<<<(N_NODES * 16 + 255) / 256, 256, 0, stream>>>(
            (const float4*)h_pre, colsum, colsq, bn_gamma + i * EMBED, bn_beta + i * EMBED,
            (float4*)h, (i != 2) ? 1 : 0);
    }

    pool_kernel<<<(N_GRAPHS * 64 + 255) / 256, 256, 0, stream>>>(gstart, h, gmean);
    pred_kernel<<<N_GRAPHS, OUT_DIM, 0, stream>>>(gmean, pred_W, pred_b, out);
}

// Round 5
// 847.229 us; speedup vs baseline: 2.3999x; 2.3999x over previous
//
#include <hip/hip_runtime.h>

#define N_NODES 100000
#define N_EDGES 1000000
#define N_GRAPHS 1000
#define EMBED 64
#define OUT_DIM 128
#define BN_EPS 1e-5f
#define NBLK ((N_NODES + 255) / 256)   // 391 scan blocks

// ---------------- one-time structure kernels ----------------

__global__ void embed_kernel(const int* __restrict__ nfeat,
                             const float* __restrict__ atom_embed,
                             float4* __restrict__ h4) {
    int idx = blockIdx.x * blockDim.x + threadIdx.x;   // one float4 each
    if (idx >= N_NODES * 16) return;
    int v = idx >> 4, q = idx & 15;
    const float4* ae = (const float4*)atom_embed;
    h4[idx] = ae[nfeat[v] * 16 + q];
}

__global__ void deg_kernel(const int* __restrict__ dst, int* __restrict__ deg) {
    int e = blockIdx.x * blockDim.x + threadIdx.x;
    if (e < N_EDGES) atomicAdd(&deg[dst[e]], 1);
}

__global__ void scan1_kernel(const int* __restrict__ deg, int* __restrict__ bsum) {
    __shared__ int sm[256];
    int v = blockIdx.x * 256 + threadIdx.x;
    sm[threadIdx.x] = (v < N_NODES) ? deg[v] : 0;
    __syncthreads();
    for (int off = 128; off > 0; off >>= 1) {
        if (threadIdx.x < off) sm[threadIdx.x] += sm[threadIdx.x + off];
        __syncthreads();
    }
    if (threadIdx.x == 0) bsum[blockIdx.x] = sm[0];
}

__global__ void scan2_kernel(const int* __restrict__ bsum, int* __restrict__ bpre) {
    __shared__ int sm[512];
    int i = threadIdx.x;
    int orig = (i < NBLK) ? bsum[i] : 0;
    sm[i] = orig;
    __syncthreads();
    for (int off = 1; off < 512; off <<= 1) {
        int val = sm[i];
        if (i >= off) val += sm[i - off];
        __syncthreads();
        sm[i] = val;
        __syncthreads();
    }
    if (i < NBLK) bpre[i] = sm[i] - orig;   // exclusive prefix of block sums
}

__global__ void scan3_kernel(const int* __restrict__ deg, const int* __restrict__ bpre,
                             int* __restrict__ rowptr, int* __restrict__ cursor) {
    __shared__ int sm[256];
    int v = blockIdx.x * 256 + threadIdx.x;
    int d = (v < N_NODES) ? deg[v] : 0;
    sm[threadIdx.x] = d;
    __syncthreads();
    for (int off = 1; off < 256; off <<= 1) {
        int val = sm[threadIdx.x];
        if (threadIdx.x >= off) val += sm[threadIdx.x - off];
        __syncthreads();
        sm[threadIdx.x] = val;
        __syncthreads();
    }
    if (v < N_NODES) {
        int ex = bpre[blockIdx.x] + sm[threadIdx.x] - d;  // exclusive scan
        rowptr[v] = ex;
        cursor[v] = ex;
    }
    if (v == 0) rowptr[N_NODES] = N_EDGES;
}

// bucket edges by dst; payload packs src (20 bits) + efeat (bits 20+)
__global__ void scatter_kernel(const int* __restrict__ src, const int* __restrict__ dst,
                               const int* __restrict__ efeat,
                               int* __restrict__ cursor, unsigned* __restrict__ ebuf) {
    int e = blockIdx.x * blockDim.x + threadIdx.x;
    if (e >= N_EDGES) return;
    int t = dst[e];
    int pos = atomicAdd(&cursor[t], 1);
    ebuf[pos] = (unsigned)src[e] | ((unsigned)efeat[e] << 20);
}

// graph_ids is sorted: find segment boundaries. gstart has N_GRAPHS+1 entries.
__global__ void gbound_kernel(const int* __restrict__ gid, int* __restrict__ gstart) {
    int v = blockIdx.x * blockDim.x + threadIdx.x;
    if (v > N_NODES) return;
    int cur  = (v < N_NODES) ? gid[v] : N_GRAPHS;
    int prev = (v == 0) ? -1 : gid[v - 1];
    for (int g = prev + 1; g <= cur; ++g) gstart[g] = v;
}

// ---------------- per-layer fused conv ----------------
// Wave = 4 x 16-lane slots; slot owns one NODE, lane = float4 slice of 64 dims.
// Gather: 2x manual unroll -> up to 8 independent 256B gathers in flight/wave.
// GEMM: t staged via wave-private LDS slab; wave-uniform ds_read_b128 broadcast;
// each Ws value reused across the wave's 4 nodes.
// NOTE: no min-wave launch bound — R4 showed forcing occupancy spills to
// scratch (FETCH 1.08GB, WRITE 882MB). Natural VGPR use is the win here.
__launch_bounds__(256)
__global__ void fused_conv_kernel(const int* __restrict__ rowptr,
                                  const unsigned* __restrict__ ebuf,
                                  const float* __restrict__ bond,   // [5,64]
                                  const float4* __restrict__ h4,
                                  const float* __restrict__ W,      // [64,64]
                                  const float* __restrict__ bias,   // [64]
                                  float* __restrict__ h_pre,
                                  float* __restrict__ colsum,
                                  float* __restrict__ colsq) {
    __shared__ float  Ws[EMBED * EMBED];     // 16 KB
    __shared__ float4 bond4[5 * 16];         // 320 B
    __shared__ float  tmat[4][4][EMBED];     // 4 KB: [wave][slot][dim], reused for BN red

    int lane = threadIdx.x & 63;
    int wblk = threadIdx.x >> 6;
    int slot = lane >> 4;       // which node of the group of 4
    int sub  = lane & 15;       // float4 index (dims 4*sub..4*sub+3)

    for (int i = threadIdx.x; i < EMBED * EMBED; i += 256) Ws[i] = W[i];
    if (threadIdx.x < 5 * 16) bond4[threadIdx.x] = ((const float4*)bond)[threadIdx.x];
    __syncthreads();

    float bj = bias[lane];
    float lsum = 0.0f, lsq = 0.0f;

    int gwid = blockIdx.x * 4 + wblk;       // global wave id
    int nw   = gridDim.x * 4;

    for (int v0 = gwid * 4; v0 < N_NODES; v0 += nw * 4) {
        int v  = v0 + slot;
        int vc = (v < N_NODES) ? v : 0;
        int rb = rowptr[vc];
        int re = (v < N_NODES) ? rowptr[vc + 1] : rb;

        float4 a = {0.f, 0.f, 0.f, 0.f};
        for (int e = rb; e < re; e += 2) {
            unsigned p0 = ebuf[e];
            int  ok1 = (e + 1 < re);
            unsigned p1 = ebuf[ok1 ? e + 1 : e];
            float m1 = ok1 ? 1.0f : 0.0f;
            int s0 = (int)(p0 & 0xFFFFFu), b0 = (int)(p0 >> 20);
            int s1 = (int)(p1 & 0xFFFFFu), b1 = (int)(p1 >> 20);
            float4 h0 = h4[s0 * 16 + sub];
            float4 h1 = h4[s1 * 16 + sub];
            float4 c0 = bond4[b0 * 16 + sub];
            float4 c1 = bond4[b1 * 16 + sub];
            a.x += fmaxf(h0.x + c0.x, 0.f) + m1 * fmaxf(h1.x + c1.x, 0.f);
            a.y += fmaxf(h0.y + c0.y, 0.f) + m1 * fmaxf(h1.y + c1.y, 0.f);
            a.z += fmaxf(h0.z + c0.z, 0.f) + m1 * fmaxf(h1.z + c1.z, 0.f);
            a.w += fmaxf(h0.w + c0.w, 0.f) + m1 * fmaxf(h1.w + c1.w, 0.f);
        }
        float inv = 1.0f / fmaxf((float)(re - rb), 1.0f);
        float4 hr = h4[vc * 16 + sub];
        float4 t;
        t.x = a.x * inv + hr.x;
        t.y = a.y * inv + hr.y;
        t.z = a.z * inv + hr.z;
        t.w = a.w * inv + hr.w;
        *(float4*)&tmat[wblk][slot][sub * 4] = t;   // wave-private; lgkmcnt guards reads

        float o0 = bj, o1 = bj, o2 = bj, o3 = bj;
#pragma unroll
        for (int dq = 0; dq < 16; ++dq) {
            float w0 = Ws[(dq * 4 + 0) * EMBED + lane];
            float w1 = Ws[(dq * 4 + 1) * EMBED + lane];
            float w2 = Ws[(dq * 4 + 2) * EMBED + lane];
            float w3 = Ws[(dq * 4 + 3) * EMBED + lane];
            float4 t0 = *(const float4*)&tmat[wblk][0][dq * 4];
            float4 t1 = *(const float4*)&tmat[wblk][1][dq * 4];
            float4 t2 = *(const float4*)&tmat[wblk][2][dq * 4];
            float4 t3 = *(const float4*)&tmat[wblk][3][dq * 4];
            o0 += t0.x * w0 + t0.y * w1 + t0.z * w2 + t0.w * w3;
            o1 += t1.x * w0 + t1.y * w1 + t1.z * w2 + t1.w * w3;
            o2 += t2.x * w0 + t2.y * w1 + t2.z * w2 + t2.w * w3;
            o3 += t3.x * w0 + t3.y * w1 + t3.z * w2 + t3.w * w3;
        }
        float oo[4] = {o0, o1, o2, o3};
#pragma unroll
        for (int k = 0; k < 4; ++k) {
            int vv = v0 + k;
            if (vv < N_NODES) {
                h_pre[vv * EMBED + lane] = oo[k];
                lsum += oo[k];
                lsq  += oo[k] * oo[k];
            }
        }
    }

    // BN partial reduction; reuse tmat (each wave writes only its own slice)
    __syncthreads();
    tmat[wblk][0][lane] = lsum;
    tmat[wblk][1][lane] = lsq;
    __syncthreads();
    if (wblk == 0) {
        float s = tmat[0][0][lane] + tmat[1][0][lane] + tmat[2][0][lane] + tmat[3][0][lane];
        float q = tmat[0][1][lane] + tmat[1][1][lane] + tmat[2][1][lane] + tmat[3][1][lane];
        atomicAdd(&colsum[lane], s);
        atomicAdd(&colsq[lane], q);
    }
}

// batchnorm + optional relu + residual (in-place update of h), float4
__global__ void bn_kernel(const float4* __restrict__ h_pre4,
                          const float* __restrict__ colsum,
                          const float* __restrict__ colsq,
                          const float* __restrict__ gamma,
                          const float* __restrict__ beta,
                          float4* __restrict__ h4,
                          int do_relu) {
    int idx = blockIdx.x * blockDim.x + threadIdx.x;   // one float4
    if (idx >= N_NODES * 16) return;
    int q = idx & 15;            // dims 4q..4q+3
    const float invN = 1.0f / (float)N_NODES;
    float4 p = h_pre4[idx];
    float4 r = h4[idx];
    float o[4] = {p.x, p.y, p.z, p.w};
    float rr[4] = {r.x, r.y, r.z, r.w};
#pragma unroll
    for (int c = 0; c < 4; ++c) {
        int j = q * 4 + c;
        float mu  = colsum[j] * invN;
        float var = colsq[j] * invN - mu * mu;
        float inv = rsqrtf(var + BN_EPS);
        float y = (o[c] - mu) * inv * gamma[j] + beta[j];
        if (do_relu) y = fmaxf(y, 0.0f);
        o[c] = y + rr[c];
    }
    float4 res = {o[0], o[1], o[2], o[3]};
    h4[idx] = res;
}

// one wave per graph: sequential coalesced mean over its node range (gid sorted)
__global__ void pool_kernel(const int* __restrict__ gstart,
                            const float* __restrict__ h,
                            float* __restrict__ gmean) {
    int g    = (blockIdx.x * blockDim.x + threadIdx.x) >> 6;
    int lane = threadIdx.x & 63;
    if (g >= N_GRAPHS) return;
    int b = gstart[g], e = gstart[g + 1];
    float s = 0.0f;
    for (int v = b; v < e; ++v) s += h[v * EMBED + lane];
    gmean[g * EMBED + lane] = s / fmaxf((float)(e - b), 1.0f);
}

// [1000,64] @ [64,128] + b, one block (128 threads) per graph
__global__ void pred_kernel(const float* __restrict__ gmean,
                            const float* __restrict__ W,   // [64,128]
                            const float* __restrict__ b,   // [128]
                            float* __restrict__ out) {
    __shared__ float gm[EMBED];
    int g = blockIdx.x;
    int j = threadIdx.x;  // 0..127
    if (j < EMBED) gm[j] = gmean[g * EMBED + j];
    __syncthreads();
    float acc = b[j];
#pragma unroll
    for (int d = 0; d < EMBED; ++d)
        acc += gm[d] * W[d * OUT_DIM + j];
    out[g * OUT_DIM + j] = acc;
}

// ---------------- launch ----------------

extern "C" void kernel_launch(void* const* d_in, const int* in_sizes, int n_in,
                              void* d_out, int out_size, void* d_ws, size_t ws_size,
                              hipStream_t stream) {
    const int*   nfeat      = (const int*)d_in[0];
    const int*   efeat      = (const int*)d_in[1];
    const int*   src        = (const int*)d_in[2];
    const int*   dst        = (const int*)d_in[3];
    const int*   gid        = (const int*)d_in[4];
    const float* atom_embed = (const float*)d_in[5];
    const float* bond_embed = (const float*)d_in[6];  // [3,5,64]
    const float* conv_W     = (const float*)d_in[7];  // [3,64,64]
    const float* conv_b     = (const float*)d_in[8];  // [3,64]
    const float* bn_gamma   = (const float*)d_in[9];  // [3,64]
    const float* bn_beta    = (const float*)d_in[10]; // [3,64]
    const float* pred_W     = (const float*)d_in[11]; // [64,128]
    const float* pred_b     = (const float*)d_in[12]; // [128]
    float* out = (float*)d_out;

    char* wsb = (char*)d_ws;
    float*    h      = (float*)wsb;                     wsb += (size_t)N_NODES * EMBED * 4;
    float*    h_pre  = (float*)wsb;                     wsb += (size_t)N_NODES * EMBED * 4;
    int*      deg    = (int*)wsb;                       wsb += (size_t)N_NODES * 4;
    int*      rowptr = (int*)wsb;                       wsb += (size_t)(N_NODES + 1) * 4;
    int*      cursor = (int*)wsb;                       wsb += (size_t)N_NODES * 4;
    int*      bsum   = (int*)wsb;                       wsb += (size_t)NBLK * 4;
    int*      bpre   = (int*)wsb;                       wsb += (size_t)NBLK * 4;
    unsigned* ebuf   = (unsigned*)wsb;                  wsb += (size_t)N_EDGES * 4;
    int*      gstart = (int*)wsb;                       wsb += (size_t)(N_GRAPHS + 1) * 4;
    float*    gmean  = (float*)wsb;                     wsb += (size_t)N_GRAPHS * EMBED * 4;
    float*    colsum = (float*)wsb;                     wsb += (size_t)EMBED * 4;
    float*    colsq  = (float*)wsb;                     wsb += (size_t)EMBED * 4;

    hipMemsetAsync(deg, 0, N_NODES * sizeof(int), stream);

    embed_kernel<<<(N_NODES * 16 + 255) / 256, 256, 0, stream>>>(nfeat, atom_embed, (float4*)h);
    deg_kernel<<<(N_EDGES + 255) / 256, 256, 0, stream>>>(dst, deg);
    scan1_kernel<<<NBLK, 256, 0, stream>>>(deg, bsum);
    scan2_kernel<<<1, 512, 0, stream>>>(bsum, bpre);
    scan3_kernel<<<NBLK, 256, 0, stream>>>(deg, bpre, rowptr, cursor);
    scatter_kernel<<<(N_EDGES + 255) / 256, 256, 0, stream>>>(src, dst, efeat, cursor, ebuf);
    gbound_kernel<<<(N_NODES + 256) / 256, 256, 0, stream>>>(gid, gstart);

    for (int i = 0; i < 3; ++i) {
        hipMemsetAsync(colsum, 0, 2 * EMBED * sizeof(float), stream);  // colsum+colsq
        fused_conv_kernel<<<2048, 256, 0, stream>>>(
            rowptr, ebuf, bond_embed + i * 5 * EMBED, (const float4*)h,
            conv_W + i * EMBED * EMBED, conv_b + i * EMBED,
            h_pre, colsum, colsq);
        bn_kernel<<<(N_NODES * 16 + 255) / 256, 256, 0, stream>>>(
            (const float4*)h_pre, colsum, colsq, bn_gamma + i * EMBED, bn_beta + i * EMBED,
            (float4*)h, (i != 2) ? 1 : 0);
    }

    pool_kernel<<<(N_GRAPHS * 64 + 255) / 256, 256, 0, stream>>>(gstart, h, gmean);
    pred_kernel<<<N_GRAPHS, OUT_DIM, 0, stream>>>(gmean, pred_W, pred_b, out);
}